// Round 1
// baseline (655.238 us; speedup 1.0000x reference)
//
#include <hip/hip_runtime.h>
#include <stdint.h>

// SubdivideMeshes: verts (N,V,3) f32, faces (F,3) i32, edges (E,2) i32,
// face_to_edge (F,3) i32.
// Out (flat f32): new_verts (N, V+E, 3) then new_faces (4F, 3) as floats
// (indices < 2^24, exact in f32).

#define GRID_S 1024
#define V_CONST (GRID_S * GRID_S)  // 1048576

typedef float f4v __attribute__((ext_vector_type(4)));
typedef float f2v __attribute__((ext_vector_type(2)));

// ---------------------------------------------------------------------------
// Kernel 1: copy verts into the head of each batch's new_verts block.
// dst row start (n*(V+E)*3) is odd-multiple -> peel to 16B alignment, then
// aligned float4 nontemporal stores (503MB of output is streaming; nt keeps
// verts resident in L2/L3 for the midpoints gathers that follow).
__global__ void copy_verts_k(const float* __restrict__ verts,
                             float* __restrict__ out,
                             int perBatch,       // V*3 (multiple of 4)
                             int rowStride3) {   // (V+E)*3 (odd)
    const int n = blockIdx.y;
    const int d0 = n * rowStride3;
    const float* __restrict__ src = verts + n * perBatch;
    float* __restrict__ dst = out + d0;

    const int pad = (4 - (d0 & 3)) & 3;          // floats until dst is 16B-aligned
    const int main4 = (perBatch - pad) >> 2;     // # of aligned float4 chunks
    const int k = blockIdx.x * blockDim.x + threadIdx.x;

    if (k < main4) {
        const int s = pad + (k << 2);
        f4v v;
        if (pad == 0) {
            // src batch base is 16B aligned and s%4==0 -> aligned vector load
            v = *reinterpret_cast<const f4v*>(src + s);
        } else {
            v[0] = src[s + 0];
            v[1] = src[s + 1];
            v[2] = src[s + 2];
            v[3] = src[s + 3];
        }
        __builtin_nontemporal_store(v, reinterpret_cast<f4v*>(dst + s));
    }
    if (k == 0) {
        const int rem = (perBatch - pad) & 3;
        for (int i = 0; i < pad; ++i) dst[i] = src[i];
        for (int i = perBatch - rem; i < perBatch; ++i) dst[i] = src[i];
    }
}

// ---------------------------------------------------------------------------
// Kernel 2: edge midpoints, batch loop fused into the thread.
// Edge int2 loaded ONCE (was 8x), 6 gathers x N batches issued from one wave
// (more memory-level parallelism), nontemporal stores for the 301MB output.
__global__ void midpoints_k(const float* __restrict__ verts,
                            const int2* __restrict__ edges,
                            float* __restrict__ out,
                            int E, int N, int rowStride3) {
    const int e = blockIdx.x * blockDim.x + threadIdx.x;
    if (e >= E) return;
    const int2 ed = edges[e];
    const int i0 = 3 * ed.x;
    const int i1 = 3 * ed.y;

    const float* __restrict__ b = verts;
    float* __restrict__ o = out + (V_CONST + e) * 3;

#pragma unroll 2
    for (int n = 0; n < N; ++n) {
        const float x = 0.5f * (b[i0 + 0] + b[i1 + 0]);
        const float y = 0.5f * (b[i0 + 1] + b[i1 + 1]);
        const float z = 0.5f * (b[i0 + 2] + b[i1 + 2]);
        __builtin_nontemporal_store(x, o + 0);
        __builtin_nontemporal_store(y, o + 1);
        __builtin_nontemporal_store(z, o + 2);
        b += V_CONST * 3;
        o += rowStride3;
    }
}

// ---------------------------------------------------------------------------
// Kernel 3: new faces. 4 faces per thread: int4 loads (3 each for faces/fte),
// 12-float stores per segment via float4 (or float2 when segment base is only
// 8B-aligned: 3F mod 4 == 2 here).
__device__ __forceinline__ void store12(float* p, f4v w0, f4v w1, f4v w2) {
    const uintptr_t a = (uintptr_t)p;
    if ((a & 15) == 0) {
        f4v* q = reinterpret_cast<f4v*>(p);
        __builtin_nontemporal_store(w0, q + 0);
        __builtin_nontemporal_store(w1, q + 1);
        __builtin_nontemporal_store(w2, q + 2);
    } else if ((a & 7) == 0) {
        f2v* q = reinterpret_cast<f2v*>(p);
        f2v a0 = {w0[0], w0[1]}, a1 = {w0[2], w0[3]};
        f2v a2 = {w1[0], w1[1]}, a3 = {w1[2], w1[3]};
        f2v a4 = {w2[0], w2[1]}, a5 = {w2[2], w2[3]};
        __builtin_nontemporal_store(a0, q + 0);
        __builtin_nontemporal_store(a1, q + 1);
        __builtin_nontemporal_store(a2, q + 2);
        __builtin_nontemporal_store(a3, q + 3);
        __builtin_nontemporal_store(a4, q + 4);
        __builtin_nontemporal_store(a5, q + 5);
    } else {
#pragma unroll
        for (int i = 0; i < 4; ++i) __builtin_nontemporal_store(w0[i], p + i);
#pragma unroll
        for (int i = 0; i < 4; ++i) __builtin_nontemporal_store(w1[i], p + 4 + i);
#pragma unroll
        for (int i = 0; i < 4; ++i) __builtin_nontemporal_store(w2[i], p + 8 + i);
    }
}

__global__ void faces_k(const int* __restrict__ faces,
                        const int* __restrict__ fte,
                        float* __restrict__ out,
                        int F, int baseOut) {
    const int t = blockIdx.x * blockDim.x + threadIdx.x;
    const int mainT = F >> 2;
    float* __restrict__ base = out + baseOut;

    if (t < mainT) {
        const int4* f4 = reinterpret_cast<const int4*>(faces) + 3 * t;
        const int4* q4 = reinterpret_cast<const int4*>(fte) + 3 * t;
        const int4 p0 = f4[0], p1 = f4[1], p2 = f4[2];
        const int4 q0 = q4[0], q1 = q4[1], q2 = q4[2];

        // faces layout: f0(a,b,c) f1(a,b,c) f2(a,b,c) f3(a,b,c) packed in p0..p2
        const float a0 = (float)p0.x, a1 = (float)p0.w, a2 = (float)p1.z, a3 = (float)p2.y;
        const float b0 = (float)p0.y, b1 = (float)p1.x, b2 = (float)p1.w, b3 = (float)p2.z;
        const float c0 = (float)p0.z, c1 = (float)p1.y, c2 = (float)p2.x, c3 = (float)p2.w;

        const float e00 = (float)(q0.x + V_CONST), e01 = (float)(q0.w + V_CONST),
                    e02 = (float)(q1.z + V_CONST), e03 = (float)(q2.y + V_CONST);
        const float e10 = (float)(q0.y + V_CONST), e11 = (float)(q1.x + V_CONST),
                    e12 = (float)(q1.w + V_CONST), e13 = (float)(q2.z + V_CONST);
        const float e20 = (float)(q0.z + V_CONST), e21 = (float)(q1.y + V_CONST),
                    e22 = (float)(q2.x + V_CONST), e23 = (float)(q2.w + V_CONST);

        const int off = 12 * t;
        const int segF = 3 * F;

        // seg0: rows [a, e2, e1]
        store12(base + off,
                (f4v){a0, e20, e10, a1}, (f4v){e21, e11, a2, e22}, (f4v){e12, a3, e23, e13});
        // seg1: rows [b, e0, e2]
        store12(base + segF + off,
                (f4v){b0, e00, e20, b1}, (f4v){e01, e21, b2, e02}, (f4v){e22, b3, e03, e23});
        // seg2: rows [c, e1, e0]
        store12(base + 2 * segF + off,
                (f4v){c0, e10, e00, c1}, (f4v){e11, e01, c2, e12}, (f4v){e02, c3, e13, e03});
        // seg3: rows [e0, e1, e2]
        store12(base + 3 * segF + off,
                (f4v){e00, e10, e20, e01}, (f4v){e11, e21, e02, e12}, (f4v){e22, e03, e13, e23});
    } else if (t == mainT) {
        // tail: F mod 4 faces, scalar
        for (int f = mainT * 4; f < F; ++f) {
            const int a = faces[3 * f + 0];
            const int b = faces[3 * f + 1];
            const int c = faces[3 * f + 2];
            const int e0 = fte[3 * f + 0] + V_CONST;
            const int e1 = fte[3 * f + 1] + V_CONST;
            const int e2 = fte[3 * f + 2] + V_CONST;
            float* o0 = base + 3 * f;
            float* o1 = o0 + 3 * F;
            float* o2 = o1 + 3 * F;
            float* o3 = o2 + 3 * F;
            o0[0] = (float)a;  o0[1] = (float)e2; o0[2] = (float)e1;
            o1[0] = (float)b;  o1[1] = (float)e0; o1[2] = (float)e2;
            o2[0] = (float)c;  o2[1] = (float)e1; o2[2] = (float)e0;
            o3[0] = (float)e0; o3[1] = (float)e1; o3[2] = (float)e2;
        }
    }
}

extern "C" void kernel_launch(void* const* d_in, const int* in_sizes, int n_in,
                              void* d_out, int out_size, void* d_ws, size_t ws_size,
                              hipStream_t stream) {
    const float* verts = (const float*)d_in[0];
    const int* faces   = (const int*)d_in[1];
    const int* edges   = (const int*)d_in[2];
    const int* fte     = (const int*)d_in[3];
    float* out = (float*)d_out;

    const int F = in_sizes[1] / 3;
    const int E = in_sizes[2] / 2;
    const int N = in_sizes[0] / (V_CONST * 3);

    const int perBatch   = V_CONST * 3;          // 3,145,728
    const int rowStride3 = (V_CONST + E) * 3;    // per-batch new_verts stride (odd)
    const int baseOut    = N * rowStride3;       // start of new_faces region

    {
        dim3 block(256);
        dim3 grid((perBatch / 4 + 255) / 256, N);
        copy_verts_k<<<grid, block, 0, stream>>>(verts, out, perBatch, rowStride3);
    }
    {
        dim3 block(256);
        dim3 grid((E + 255) / 256);
        midpoints_k<<<grid, block, 0, stream>>>(verts, (const int2*)edges, out,
                                                E, N, rowStride3);
    }
    {
        const int mainT = F >> 2;
        dim3 block(256);
        dim3 grid((mainT + 1 + 255) / 256);
        faces_k<<<grid, block, 0, stream>>>(faces, fte, out, F, baseOut);
    }
}

// Round 2
// 650.129 us; speedup vs baseline: 1.0079x; 1.0079x over previous
//
#include <hip/hip_runtime.h>
#include <stdint.h>

// SubdivideMeshes: verts (N,V,3) f32, faces (F,3) i32, edges (E,2) i32,
// face_to_edge (F,3) i32.
// Out (flat f32): new_verts (N, V+E, 3) then new_faces (4F, 3) as floats
// (indices < 2^24, exact in f32).
//
// Single fused dispatch, blockIdx.x-partitioned:
//   [0, Bcopy)            : copy verts -> head of each batch's new_verts
//   [Bcopy, Bcopy+Bmid)   : edge midpoints (batch loop in-thread)
//   [Bcopy+Bmid, ...)     : new faces
// Plain (cached) stores everywhere: the harness's fillBuffer proves plain
// streaming stores hit 6.3 TB/s on this buffer.

#define GRID_S 1024
#define V_CONST (GRID_S * GRID_S)        // 1,048,576
#define PER_BATCH (V_CONST * 3)          // 3,145,728 floats per batch of verts
#define CHUNKS_PER_BATCH (PER_BATCH / 4 / 256)  // 3072 blocks per batch (exact)

typedef float f4v __attribute__((ext_vector_type(4)));
typedef float f2v __attribute__((ext_vector_type(2)));

__device__ __forceinline__ void store12(float* p, f4v w0, f4v w1, f4v w2) {
    const uintptr_t a = (uintptr_t)p;
    if ((a & 15) == 0) {
        f4v* q = reinterpret_cast<f4v*>(p);
        q[0] = w0; q[1] = w1; q[2] = w2;
    } else if ((a & 7) == 0) {
        f2v* q = reinterpret_cast<f2v*>(p);
        q[0] = (f2v){w0[0], w0[1]};
        q[1] = (f2v){w0[2], w0[3]};
        q[2] = (f2v){w1[0], w1[1]};
        q[3] = (f2v){w1[2], w1[3]};
        q[4] = (f2v){w2[0], w2[1]};
        q[5] = (f2v){w2[2], w2[3]};
    } else {
#pragma unroll
        for (int i = 0; i < 4; ++i) p[i] = w0[i];
#pragma unroll
        for (int i = 0; i < 4; ++i) p[4 + i] = w1[i];
#pragma unroll
        for (int i = 0; i < 4; ++i) p[8 + i] = w2[i];
    }
}

__global__ __launch_bounds__(256) void fused_k(
    const float* __restrict__ verts,
    const int2*  __restrict__ edges,
    const int*   __restrict__ faces,
    const int*   __restrict__ fte,
    float* __restrict__ out,
    int E, int F, int N, int rowStride3, int baseOut,
    int Bcopy, int Bmid) {

    const int b = blockIdx.x;
    const int tid = threadIdx.x;

    if (b < Bcopy) {
        // ---------------- phase A: verts copy (dst-aligned float4) ---------
        const int n  = b / CHUNKS_PER_BATCH;      // constexpr divisor -> magic mul
        const int cb = b - n * CHUNKS_PER_BATCH;
        const int d0 = n * rowStride3;            // odd stride -> per-batch align
        const float* __restrict__ src = verts + n * PER_BATCH;
        float* __restrict__ dst = out + d0;
        const int pad = (4 - (d0 & 3)) & 3;       // floats until dst 16B-aligned
        const int main4 = (PER_BATCH - pad) >> 2;
        const int k = cb * 256 + tid;
        if (k < main4) {
            const int s = pad + (k << 2);
            f4v v;
            if (pad == 0) {
                v = *reinterpret_cast<const f4v*>(src + s);
            } else {
                v[0] = src[s + 0];
                v[1] = src[s + 1];
                v[2] = src[s + 2];
                v[3] = src[s + 3];
            }
            *reinterpret_cast<f4v*>(dst + s) = v;
        }
        if (k == 0) {
            const int rem = (PER_BATCH - pad) & 3;
            for (int i = 0; i < pad; ++i) dst[i] = src[i];
            for (int i = PER_BATCH - rem; i < PER_BATCH; ++i) dst[i] = src[i];
        }
        return;
    }

    if (b < Bcopy + Bmid) {
        // ---------------- phase B: edge midpoints --------------------------
        const int e = (b - Bcopy) * 256 + tid;
        if (e >= E) return;
        const int2 ed = edges[e];
        const int i0 = 3 * ed.x;
        const int i1 = 3 * ed.y;
        const float* __restrict__ vb = verts;
        float* __restrict__ o = out + (V_CONST + e) * 3;
#pragma unroll 2
        for (int n = 0; n < N; ++n) {
            const float x = 0.5f * (vb[i0 + 0] + vb[i1 + 0]);
            const float y = 0.5f * (vb[i0 + 1] + vb[i1 + 1]);
            const float z = 0.5f * (vb[i0 + 2] + vb[i1 + 2]);
            o[0] = x; o[1] = y; o[2] = z;
            vb += PER_BATCH;
            o  += rowStride3;
        }
        return;
    }

    // -------------------- phase C: new faces -------------------------------
    const int t = (b - Bcopy - Bmid) * 256 + tid;
    const int mainT = F >> 2;
    float* __restrict__ base = out + baseOut;

    if (t < mainT) {
        const int4* f4 = reinterpret_cast<const int4*>(faces) + 3 * t;
        const int4* q4 = reinterpret_cast<const int4*>(fte) + 3 * t;
        const int4 p0 = f4[0], p1 = f4[1], p2 = f4[2];
        const int4 q0 = q4[0], q1 = q4[1], q2 = q4[2];

        const float a0 = (float)p0.x, a1 = (float)p0.w, a2 = (float)p1.z, a3 = (float)p2.y;
        const float b0 = (float)p0.y, b1 = (float)p1.x, b2 = (float)p1.w, b3 = (float)p2.z;
        const float c0 = (float)p0.z, c1 = (float)p1.y, c2 = (float)p2.x, c3 = (float)p2.w;

        const float e00 = (float)(q0.x + V_CONST), e01 = (float)(q0.w + V_CONST),
                    e02 = (float)(q1.z + V_CONST), e03 = (float)(q2.y + V_CONST);
        const float e10 = (float)(q0.y + V_CONST), e11 = (float)(q1.x + V_CONST),
                    e12 = (float)(q1.w + V_CONST), e13 = (float)(q2.z + V_CONST);
        const float e20 = (float)(q0.z + V_CONST), e21 = (float)(q1.y + V_CONST),
                    e22 = (float)(q2.x + V_CONST), e23 = (float)(q2.w + V_CONST);

        const int off = 12 * t;
        const int segF = 3 * F;

        store12(base + off,
                (f4v){a0, e20, e10, a1}, (f4v){e21, e11, a2, e22}, (f4v){e12, a3, e23, e13});
        store12(base + segF + off,
                (f4v){b0, e00, e20, b1}, (f4v){e01, e21, b2, e02}, (f4v){e22, b3, e03, e23});
        store12(base + 2 * segF + off,
                (f4v){c0, e10, e00, c1}, (f4v){e11, e01, c2, e12}, (f4v){e02, c3, e13, e03});
        store12(base + 3 * segF + off,
                (f4v){e00, e10, e20, e01}, (f4v){e11, e21, e02, e12}, (f4v){e22, e03, e13, e23});
    } else if (t == mainT) {
        for (int f = mainT * 4; f < F; ++f) {
            const int a = faces[3 * f + 0];
            const int bb = faces[3 * f + 1];
            const int c = faces[3 * f + 2];
            const int e0 = fte[3 * f + 0] + V_CONST;
            const int e1 = fte[3 * f + 1] + V_CONST;
            const int e2 = fte[3 * f + 2] + V_CONST;
            float* o0 = base + 3 * f;
            float* o1 = o0 + 3 * F;
            float* o2 = o1 + 3 * F;
            float* o3 = o2 + 3 * F;
            o0[0] = (float)a;  o0[1] = (float)e2; o0[2] = (float)e1;
            o1[0] = (float)bb; o1[1] = (float)e0; o1[2] = (float)e2;
            o2[0] = (float)c;  o2[1] = (float)e1; o2[2] = (float)e0;
            o3[0] = (float)e0; o3[1] = (float)e1; o3[2] = (float)e2;
        }
    }
}

extern "C" void kernel_launch(void* const* d_in, const int* in_sizes, int n_in,
                              void* d_out, int out_size, void* d_ws, size_t ws_size,
                              hipStream_t stream) {
    const float* verts = (const float*)d_in[0];
    const int* faces   = (const int*)d_in[1];
    const int* edges   = (const int*)d_in[2];
    const int* fte     = (const int*)d_in[3];
    float* out = (float*)d_out;

    const int F = in_sizes[1] / 3;
    const int E = in_sizes[2] / 2;
    const int N = in_sizes[0] / (V_CONST * 3);

    const int rowStride3 = (V_CONST + E) * 3;    // per-batch new_verts stride (odd)
    const int baseOut    = N * rowStride3;       // start of new_faces region

    const int Bcopy = N * CHUNKS_PER_BATCH;      // 8 * 3072 = 24576
    const int Bmid  = (E + 255) / 256;           // 12273
    const int Bfac  = ((F >> 2) + 1 + 255) / 256;  // 2045
    const int blocks = Bcopy + Bmid + Bfac;

    fused_k<<<blocks, 256, 0, stream>>>(verts, (const int2*)edges, faces, fte,
                                        out, E, F, N, rowStride3, baseOut,
                                        Bcopy, Bmid);
}